// Round 1
// baseline (2762.799 us; speedup 1.0000x reference)
//
#include <hip/hip_runtime.h>
#include <hip/hip_bf16.h>
#include <math.h>

#define N_NODES 50000
#define E_EDGES 800000
#define M_PATHS 3
#define IN_F    128
#define H_HEADS 8
#define O_DIM   32
#define D_DIM   256   // H*O
#define HID_DIM 128
#define NEG_SLOPE 0.2f

// ---------------- GEMM: feat = h @ W  (fp32, LDS-tiled 64x64) ----------------
__global__ __launch_bounds__(256) void gemm_feat(const float* __restrict__ h,
                                                 const float* __restrict__ W,
                                                 float* __restrict__ feat) {
    __shared__ float As[16][64 + 1];  // [k][m]
    __shared__ float Bs[16][64 + 1];  // [k][n]
    const int bm = blockIdx.x;
    const int bn = blockIdx.y;
    const int tid = threadIdx.x;
    const int tm = tid / 16, tn = tid % 16;   // 16x16 thread tile, 4x4 each
    const int row0 = bm * 64, col0 = bn * 64;
    float acc[4][4] = {};

    for (int k0 = 0; k0 < IN_F; k0 += 16) {
        for (int i = tid; i < 64 * 16; i += 256) {
            int m = i / 16, k = i % 16;
            int r = row0 + m;
            As[k][m] = (r < N_NODES) ? h[(size_t)r * IN_F + k0 + k] : 0.f;
        }
        for (int i = tid; i < 16 * 64; i += 256) {
            int k = i / 64, n = i % 64;
            Bs[k][n] = W[(size_t)(k0 + k) * D_DIM + col0 + n];
        }
        __syncthreads();
        #pragma unroll
        for (int k = 0; k < 16; ++k) {
            float a[4], b[4];
            #pragma unroll
            for (int i = 0; i < 4; i++) a[i] = As[k][tm * 4 + i];
            #pragma unroll
            for (int j = 0; j < 4; j++) b[j] = Bs[k][tn * 4 + j];
            #pragma unroll
            for (int i = 0; i < 4; i++)
                #pragma unroll
                for (int j = 0; j < 4; j++)
                    acc[i][j] += a[i] * b[j];
        }
        __syncthreads();
    }
    #pragma unroll
    for (int i = 0; i < 4; i++) {
        int r = row0 + tm * 4 + i;
        if (r < N_NODES) {
            #pragma unroll
            for (int j = 0; j < 4; j++)
                feat[(size_t)r * D_DIM + col0 + tn * 4 + j] = acc[i][j];
        }
    }
}

// ---------------- el/er: per (node, head) dot with attn vectors ----------------
__global__ void attn_dots(const float* __restrict__ feat,
                          const float* __restrict__ al,
                          const float* __restrict__ ar,
                          float* __restrict__ el, float* __restrict__ er) {
    int idx = blockIdx.x * blockDim.x + threadIdx.x;   // n*H + h
    if (idx >= N_NODES * H_HEADS) return;
    int n = idx / H_HEADS, hh = idx % H_HEADS;
    const float* f = feat + (size_t)n * D_DIM + hh * O_DIM;
    const float* a = al + hh * O_DIM;
    const float* b = ar + hh * O_DIM;
    float sl = 0.f, sr = 0.f;
    #pragma unroll
    for (int o = 0; o < O_DIM; o++) { float v = f[o]; sl += v * a[o]; sr += v * b[o]; }
    el[idx] = sl; er[idx] = sr;
}

// ---------------- softmax denominator (no max pass; e is small) ----------------
__global__ void edge_den(const int* __restrict__ src, const int* __restrict__ dst,
                         const float* __restrict__ el, const float* __restrict__ er,
                         float* __restrict__ den) {
    int i = blockIdx.x * blockDim.x + threadIdx.x;     // e*H + h
    if (i >= E_EDGES * H_HEADS) return;
    int e = i / H_HEADS, hh = i % H_HEADS;
    int s = src[e], d = dst[e];
    float x = el[s * H_HEADS + hh] + er[d * H_HEADS + hh];
    x = x > 0.f ? x : NEG_SLOPE * x;
    atomicAdd(&den[d * H_HEADS + hh], expf(x));
}

// ---------------- scatter: z[dst] += alpha * feat[src] ----------------
__global__ __launch_bounds__(256) void scatter_out(const int* __restrict__ src,
                                                   const int* __restrict__ dst,
                                                   const float* __restrict__ el,
                                                   const float* __restrict__ er,
                                                   const float* __restrict__ den,
                                                   const float* __restrict__ feat,
                                                   float* __restrict__ z) {
    const int t = threadIdx.x;      // component d in [0,256)
    const int hh = t >> 5;          // head
    for (int e = blockIdx.x; e < E_EDGES; e += gridDim.x) {
        int s = src[e], d = dst[e];
        float x = el[s * H_HEADS + hh] + er[d * H_HEADS + hh];
        x = x > 0.f ? x : NEG_SLOPE * x;
        float ex = expf(x);
        float dn = den[d * H_HEADS + hh];
        float alpha = ex / (dn == 0.f ? 1.f : dn);
        float v = alpha * feat[(size_t)s * D_DIM + t];
        atomicAdd(&z[(size_t)d * D_DIM + t], v);
    }
}

// ---------------- bias + ELU in place ----------------
__global__ void bias_elu(float* __restrict__ z, const float* __restrict__ bias) {
    int i = blockIdx.x * blockDim.x + threadIdx.x;
    if (i >= N_NODES * D_DIM) return;
    float x = z[i] + bias[i & (D_DIM - 1)];
    z[i] = x > 0.f ? x : expm1f(x);
}

// ---------------- semantic attention: accumulate sum_n w[n,m] ----------------
#define ROWS_PER_BLK 16
__global__ __launch_bounds__(128) void semantic_w(const float* __restrict__ z,
                                                  const float* __restrict__ W1,
                                                  const float* __restrict__ b1,
                                                  const float* __restrict__ W2,
                                                  float* __restrict__ wsum) {
    __shared__ float zs[ROWS_PER_BLK][D_DIM];
    __shared__ float red[128];
    const int t = threadIdx.x;
    const size_t r0 = (size_t)blockIdx.x * ROWS_PER_BLK;  // row in [0, M*N)
    const int m = (int)(r0 / N_NODES);                    // 50000 % 16 == 0 -> no straddle

    for (int i = t; i < ROWS_PER_BLK * D_DIM; i += 128) {
        int rr = i / D_DIM;
        zs[rr][i % D_DIM] = z[(r0 + rr) * D_DIM + (i % D_DIM)];
    }
    __syncthreads();

    float acc[ROWS_PER_BLK];
    float bb = b1[t];
    #pragma unroll
    for (int rr = 0; rr < ROWS_PER_BLK; rr++) acc[rr] = bb;
    for (int d = 0; d < D_DIM; d++) {
        float w = W1[(size_t)d * HID_DIM + t];
        #pragma unroll
        for (int rr = 0; rr < ROWS_PER_BLK; rr++) acc[rr] += zs[rr][d] * w;
    }
    float w2 = W2[t];
    float part = 0.f;
    #pragma unroll
    for (int rr = 0; rr < ROWS_PER_BLK; rr++) part += tanhf(acc[rr]) * w2;

    red[t] = part;
    __syncthreads();
    for (int s = 64; s > 0; s >>= 1) {
        if (t < s) red[t] += red[t + s];
        __syncthreads();
    }
    if (t == 0) atomicAdd(&wsum[m], red[0]);
}

// ---------------- beta = softmax(mean_n w) ----------------
__global__ void compute_beta(const float* __restrict__ wsum, float* __restrict__ beta) {
    float w0 = wsum[0] / N_NODES, w1 = wsum[1] / N_NODES, w2 = wsum[2] / N_NODES;
    float mx = fmaxf(w0, fmaxf(w1, w2));
    float e0 = expf(w0 - mx), e1 = expf(w1 - mx), e2 = expf(w2 - mx);
    float s = e0 + e1 + e2;
    beta[0] = e0 / s; beta[1] = e1 / s; beta[2] = e2 / s;
}

// ---------------- final: out = sum_m beta[m] * z[m] ----------------
__global__ void final_mix(const float* __restrict__ z, const float* __restrict__ beta,
                          float* __restrict__ out) {
    int i = blockIdx.x * blockDim.x + threadIdx.x;
    if (i >= N_NODES * D_DIM) return;
    const size_t stride = (size_t)N_NODES * D_DIM;
    out[i] = beta[0] * z[i] + beta[1] * z[stride + i] + beta[2] * z[2 * stride + i];
}

extern "C" void kernel_launch(void* const* d_in, const int* in_sizes, int n_in,
                              void* d_out, int out_size, void* d_ws, size_t ws_size,
                              hipStream_t stream) {
    const float* h        = (const float*)d_in[0];
    const int*   eidx     = (const int*)d_in[1];
    const float* W        = (const float*)d_in[2];
    const float* attn_l   = (const float*)d_in[3];
    const float* attn_r   = (const float*)d_in[4];
    const float* bias     = (const float*)d_in[5];
    const float* sem_W1   = (const float*)d_in[6];
    const float* sem_b1   = (const float*)d_in[7];
    const float* sem_W2   = (const float*)d_in[8];
    float* out = (float*)d_out;

    float* ws   = (float*)d_ws;
    float* z    = ws;                                        // M*N*D
    float* feat = z + (size_t)M_PATHS * N_NODES * D_DIM;     // N*D (reused per metapath)
    float* el   = feat + (size_t)N_NODES * D_DIM;            // N*H
    float* er   = el + N_NODES * H_HEADS;                    // N*H
    float* den  = er + N_NODES * H_HEADS;                    // N*H
    float* wsum = den + N_NODES * H_HEADS;                   // 8
    float* beta = wsum + 8;                                  // 8

    hipMemsetAsync(z, 0, (size_t)M_PATHS * N_NODES * D_DIM * sizeof(float), stream);
    hipMemsetAsync(wsum, 0, 16 * sizeof(float), stream);

    for (int m = 0; m < M_PATHS; ++m) {
        const float* hm  = h + (size_t)m * N_NODES * IN_F;
        const float* Wm  = W + (size_t)m * IN_F * D_DIM;
        const int*   src = eidx + (size_t)m * 2 * E_EDGES;
        const int*   dst = src + E_EDGES;
        float*       zm  = z + (size_t)m * N_NODES * D_DIM;

        hipMemsetAsync(den, 0, N_NODES * H_HEADS * sizeof(float), stream);

        dim3 g1((N_NODES + 63) / 64, D_DIM / 64);
        gemm_feat<<<g1, 256, 0, stream>>>(hm, Wm, feat);

        attn_dots<<<(N_NODES * H_HEADS + 255) / 256, 256, 0, stream>>>(
            feat, attn_l + m * H_HEADS * O_DIM, attn_r + m * H_HEADS * O_DIM, el, er);

        edge_den<<<(E_EDGES * H_HEADS + 255) / 256, 256, 0, stream>>>(src, dst, el, er, den);

        scatter_out<<<16384, 256, 0, stream>>>(src, dst, el, er, den, feat, zm);

        bias_elu<<<(N_NODES * D_DIM + 255) / 256, 256, 0, stream>>>(zm, bias + m * D_DIM);
    }

    semantic_w<<<M_PATHS * N_NODES / ROWS_PER_BLK, 128, 0, stream>>>(
        z, sem_W1, sem_b1, sem_W2, wsum);
    compute_beta<<<1, 1, 0, stream>>>(wsum, beta);
    final_mix<<<(N_NODES * D_DIM + 255) / 256, 256, 0, stream>>>(z, beta, out);
}

// Round 2
// 1946.030 us; speedup vs baseline: 1.4197x; 1.4197x over previous
//
#include <hip/hip_runtime.h>
#include <hip/hip_bf16.h>
#include <math.h>

#define N_NODES 50000
#define E_EDGES 800000
#define M_PATHS 3
#define IN_F    128
#define H_HEADS 8
#define O_DIM   32
#define D_DIM   256   // H*O
#define HID_DIM 128
#define NEG_SLOPE 0.2f

// ---------------- GEMM: feat = h @ W  (fp32, LDS-tiled 64x64) ----------------
__global__ __launch_bounds__(256) void gemm_feat(const float* __restrict__ h,
                                                 const float* __restrict__ W,
                                                 float* __restrict__ feat) {
    __shared__ float As[16][64 + 1];  // [k][m]
    __shared__ float Bs[16][64 + 1];  // [k][n]
    const int bm = blockIdx.x;
    const int bn = blockIdx.y;
    const int tid = threadIdx.x;
    const int tm = tid / 16, tn = tid % 16;   // 16x16 thread tile, 4x4 each
    const int row0 = bm * 64, col0 = bn * 64;
    float acc[4][4] = {};

    for (int k0 = 0; k0 < IN_F; k0 += 16) {
        for (int i = tid; i < 64 * 16; i += 256) {
            int m = i / 16, k = i % 16;
            int r = row0 + m;
            As[k][m] = (r < N_NODES) ? h[(size_t)r * IN_F + k0 + k] : 0.f;
        }
        for (int i = tid; i < 16 * 64; i += 256) {
            int k = i / 64, n = i % 64;
            Bs[k][n] = W[(size_t)(k0 + k) * D_DIM + col0 + n];
        }
        __syncthreads();
        #pragma unroll
        for (int k = 0; k < 16; ++k) {
            float a[4], b[4];
            #pragma unroll
            for (int i = 0; i < 4; i++) a[i] = As[k][tm * 4 + i];
            #pragma unroll
            for (int j = 0; j < 4; j++) b[j] = Bs[k][tn * 4 + j];
            #pragma unroll
            for (int i = 0; i < 4; i++)
                #pragma unroll
                for (int j = 0; j < 4; j++)
                    acc[i][j] += a[i] * b[j];
        }
        __syncthreads();
    }
    #pragma unroll
    for (int i = 0; i < 4; i++) {
        int r = row0 + tm * 4 + i;
        if (r < N_NODES) {
            #pragma unroll
            for (int j = 0; j < 4; j++)
                feat[(size_t)r * D_DIM + col0 + tn * 4 + j] = acc[i][j];
        }
    }
}

// ---------------- el/er: per (node, head) dot with attn vectors ----------------
__global__ void attn_dots(const float* __restrict__ feat,
                          const float* __restrict__ al,
                          const float* __restrict__ ar,
                          float* __restrict__ el, float* __restrict__ er) {
    int idx = blockIdx.x * blockDim.x + threadIdx.x;   // n*H + h
    if (idx >= N_NODES * H_HEADS) return;
    int n = idx / H_HEADS, hh = idx % H_HEADS;
    const float* f = feat + (size_t)n * D_DIM + hh * O_DIM;
    const float* a = al + hh * O_DIM;
    const float* b = ar + hh * O_DIM;
    float sl = 0.f, sr = 0.f;
    #pragma unroll
    for (int o = 0; o < O_DIM; o++) { float v = f[o]; sl += v * a[o]; sr += v * b[o]; }
    el[idx] = sl; er[idx] = sr;
}

// ---------------- CSR build: in-degree count ----------------
__global__ void count_deg(const int* __restrict__ dst, int* __restrict__ deg) {
    int e = blockIdx.x * blockDim.x + threadIdx.x;
    if (e < E_EDGES) atomicAdd(&deg[dst[e]], 1);
}

// ---------------- exclusive scan over deg -> rowptr (single block) ----------------
#define SCAN_T 1024
__global__ __launch_bounds__(SCAN_T) void exscan_deg(const int* __restrict__ deg,
                                                     int* __restrict__ rowptr) {
    __shared__ int part[SCAN_T];
    const int t = threadIdx.x;
    const int CH = (N_NODES + SCAN_T - 1) / SCAN_T;   // 49
    const int base = t * CH;
    int sum = 0;
    for (int i = 0; i < CH; i++) {
        int idx = base + i;
        if (idx < N_NODES) sum += deg[idx];
    }
    part[t] = sum;
    __syncthreads();
    // Hillis-Steele inclusive scan of partials
    for (int off = 1; off < SCAN_T; off <<= 1) {
        int v = (t >= off) ? part[t - off] : 0;
        __syncthreads();
        part[t] += v;
        __syncthreads();
    }
    int run = (t == 0) ? 0 : part[t - 1];
    for (int i = 0; i < CH; i++) {
        int idx = base + i;
        if (idx < N_NODES) { rowptr[idx] = run; run += deg[idx]; }
    }
    if (t == SCAN_T - 1) rowptr[N_NODES] = part[SCAN_T - 1];
}

// ---------------- fill buckets: place edge in dst bucket, write ex for 8 heads ----------------
__global__ void fill_bucket(const int* __restrict__ src, const int* __restrict__ dst,
                            const float* __restrict__ el, const float* __restrict__ er,
                            const int* __restrict__ rowptr, int* __restrict__ cursor,
                            int* __restrict__ bsrc, float* __restrict__ exb) {
    int e = blockIdx.x * blockDim.x + threadIdx.x;
    if (e >= E_EDGES) return;
    int s = src[e], d = dst[e];
    int j = rowptr[d] + atomicAdd(&cursor[d], 1);
    bsrc[j] = s;
    #pragma unroll
    for (int h = 0; h < H_HEADS; h++) {
        float x = el[s * H_HEADS + h] + er[d * H_HEADS + h];
        x = x > 0.f ? x : NEG_SLOPE * x;
        exb[(size_t)j * H_HEADS + h] = expf(x);
    }
}

// ---------------- gather: z[d] = elu( (sum_j ex_j * feat[src_j]) / den + bias ) ----------------
__global__ __launch_bounds__(256) void gather_z(const int* __restrict__ rowptr,
                                                const int* __restrict__ bsrc,
                                                const float* __restrict__ exb,
                                                const float* __restrict__ feat,
                                                const float* __restrict__ bias,
                                                float* __restrict__ z) {
    const int d = blockIdx.x;
    const int t = threadIdx.x;
    const int hh = t >> 5;
    const int j0 = rowptr[d], j1 = rowptr[d + 1];

    float den = 0.f;
    for (int j = j0; j < j1; j++) den += exb[(size_t)j * H_HEADS + hh];

    float acc = 0.f;
    for (int j = j0; j < j1; j++) {
        int s = bsrc[j];
        acc += exb[(size_t)j * H_HEADS + hh] * feat[(size_t)s * D_DIM + t];
    }
    float x = acc / (den == 0.f ? 1.f : den) + bias[t];
    z[(size_t)d * D_DIM + t] = x > 0.f ? x : expm1f(x);
}

// ---------------- semantic attention: accumulate sum_n w[n,m] ----------------
#define ROWS_PER_BLK 16
__global__ __launch_bounds__(128) void semantic_w(const float* __restrict__ z,
                                                  const float* __restrict__ W1,
                                                  const float* __restrict__ b1,
                                                  const float* __restrict__ W2,
                                                  float* __restrict__ wsum) {
    __shared__ float zs[ROWS_PER_BLK][D_DIM];
    __shared__ float red[128];
    const int t = threadIdx.x;
    const size_t r0 = (size_t)blockIdx.x * ROWS_PER_BLK;  // row in [0, M*N)
    const int m = (int)(r0 / N_NODES);                    // 50000 % 16 == 0 -> no straddle

    for (int i = t; i < ROWS_PER_BLK * D_DIM; i += 128) {
        int rr = i / D_DIM;
        zs[rr][i % D_DIM] = z[(r0 + rr) * D_DIM + (i % D_DIM)];
    }
    __syncthreads();

    float acc[ROWS_PER_BLK];
    float bb = b1[t];
    #pragma unroll
    for (int rr = 0; rr < ROWS_PER_BLK; rr++) acc[rr] = bb;
    for (int d = 0; d < D_DIM; d++) {
        float w = W1[(size_t)d * HID_DIM + t];
        #pragma unroll
        for (int rr = 0; rr < ROWS_PER_BLK; rr++) acc[rr] += zs[rr][d] * w;
    }
    float w2 = W2[t];
    float part = 0.f;
    #pragma unroll
    for (int rr = 0; rr < ROWS_PER_BLK; rr++) part += tanhf(acc[rr]) * w2;

    red[t] = part;
    __syncthreads();
    for (int s = 64; s > 0; s >>= 1) {
        if (t < s) red[t] += red[t + s];
        __syncthreads();
    }
    if (t == 0) atomicAdd(&wsum[m], red[0]);
}

// ---------------- beta = softmax(mean_n w) ----------------
__global__ void compute_beta(const float* __restrict__ wsum, float* __restrict__ beta) {
    float w0 = wsum[0] / N_NODES, w1 = wsum[1] / N_NODES, w2 = wsum[2] / N_NODES;
    float mx = fmaxf(w0, fmaxf(w1, w2));
    float e0 = expf(w0 - mx), e1 = expf(w1 - mx), e2 = expf(w2 - mx);
    float s = e0 + e1 + e2;
    beta[0] = e0 / s; beta[1] = e1 / s; beta[2] = e2 / s;
}

// ---------------- final: out = sum_m beta[m] * z[m] ----------------
__global__ void final_mix(const float* __restrict__ z, const float* __restrict__ beta,
                          float* __restrict__ out) {
    int i = blockIdx.x * blockDim.x + threadIdx.x;
    if (i >= N_NODES * D_DIM) return;
    const size_t stride = (size_t)N_NODES * D_DIM;
    out[i] = beta[0] * z[i] + beta[1] * z[stride + i] + beta[2] * z[2 * stride + i];
}

extern "C" void kernel_launch(void* const* d_in, const int* in_sizes, int n_in,
                              void* d_out, int out_size, void* d_ws, size_t ws_size,
                              hipStream_t stream) {
    const float* h        = (const float*)d_in[0];
    const int*   eidx     = (const int*)d_in[1];
    const float* W        = (const float*)d_in[2];
    const float* attn_l   = (const float*)d_in[3];
    const float* attn_r   = (const float*)d_in[4];
    const float* bias     = (const float*)d_in[5];
    const float* sem_W1   = (const float*)d_in[6];
    const float* sem_b1   = (const float*)d_in[7];
    const float* sem_W2   = (const float*)d_in[8];
    float* out = (float*)d_out;

    float* ws   = (float*)d_ws;
    float* z    = ws;                                        // M*N*D           153.6 MB
    float* feat = z + (size_t)M_PATHS * N_NODES * D_DIM;     // N*D              51.2 MB
    float* el   = feat + (size_t)N_NODES * D_DIM;            // N*H
    float* er   = el + N_NODES * H_HEADS;                    // N*H
    float* exb  = er + N_NODES * H_HEADS;                    // E*H              25.6 MB
    float* wsum = exb + (size_t)E_EDGES * H_HEADS;           // 8
    float* beta = wsum + 8;                                  // 8
    int*   bsrc   = (int*)(beta + 8);                        // E                 3.2 MB
    int*   rowptr = bsrc + E_EDGES;                          // N+1
    int*   deg    = rowptr + N_NODES + 1;                    // N
    int*   cursor = deg + N_NODES;                           // N

    hipMemsetAsync(wsum, 0, 16 * sizeof(float), stream);

    for (int m = 0; m < M_PATHS; ++m) {
        const float* hm  = h + (size_t)m * N_NODES * IN_F;
        const float* Wm  = W + (size_t)m * IN_F * D_DIM;
        const int*   src = eidx + (size_t)m * 2 * E_EDGES;
        const int*   dst = src + E_EDGES;
        float*       zm  = z + (size_t)m * N_NODES * D_DIM;

        hipMemsetAsync(deg, 0, 2 * N_NODES * sizeof(int), stream);  // deg + cursor

        dim3 g1((N_NODES + 63) / 64, D_DIM / 64);
        gemm_feat<<<g1, 256, 0, stream>>>(hm, Wm, feat);

        attn_dots<<<(N_NODES * H_HEADS + 255) / 256, 256, 0, stream>>>(
            feat, attn_l + m * H_HEADS * O_DIM, attn_r + m * H_HEADS * O_DIM, el, er);

        count_deg<<<(E_EDGES + 255) / 256, 256, 0, stream>>>(dst, deg);
        exscan_deg<<<1, SCAN_T, 0, stream>>>(deg, rowptr);
        fill_bucket<<<(E_EDGES + 255) / 256, 256, 0, stream>>>(
            src, dst, el, er, rowptr, cursor, bsrc, exb);

        gather_z<<<N_NODES, 256, 0, stream>>>(rowptr, bsrc, exb, feat,
                                              bias + m * D_DIM, zm);
    }

    semantic_w<<<M_PATHS * N_NODES / ROWS_PER_BLK, 128, 0, stream>>>(
        z, sem_W1, sem_b1, sem_W2, wsum);
    compute_beta<<<1, 1, 0, stream>>>(wsum, beta);
    final_mix<<<(N_NODES * D_DIM + 255) / 256, 256, 0, stream>>>(z, beta, out);
}

// Round 3
// 1402.001 us; speedup vs baseline: 1.9706x; 1.3880x over previous
//
#include <hip/hip_runtime.h>
#include <hip/hip_bf16.h>
#include <math.h>

#define N_NODES 50000
#define E_EDGES 800000
#define M_PATHS 3
#define IN_F    128
#define H_HEADS 8
#define O_DIM   32
#define D_DIM   256   // H*O
#define HID_DIM 128
#define NEG_SLOPE 0.2f

__device__ __forceinline__ float bflo(unsigned w) { return __uint_as_float(w << 16); }
__device__ __forceinline__ float bfhi(unsigned w) { return __uint_as_float(w & 0xffff0000u); }
__device__ __forceinline__ unsigned pk_bf16(float a, float b) {
    __hip_bfloat16 ha = __float2bfloat16(a), hb = __float2bfloat16(b);
    unsigned short ua = *(unsigned short*)&ha, ub = *(unsigned short*)&hb;
    return (unsigned)ua | ((unsigned)ub << 16);
}

// ------- GEMM: featb(bf16 packed) = h @ W  (fp32 compute, LDS-tiled 64x64) -------
__global__ __launch_bounds__(256) void gemm_feat(const float* __restrict__ h,
                                                 const float* __restrict__ W,
                                                 unsigned* __restrict__ featb) {
    __shared__ float As[16][64 + 1];  // [k][m]
    __shared__ float Bs[16][64 + 1];  // [k][n]
    const int bm = blockIdx.x;
    const int bn = blockIdx.y;
    const int tid = threadIdx.x;
    const int tm = tid / 16, tn = tid % 16;   // 16x16 thread tile, 4x4 each
    const int row0 = bm * 64, col0 = bn * 64;
    float acc[4][4] = {};

    for (int k0 = 0; k0 < IN_F; k0 += 16) {
        for (int i = tid; i < 64 * 16; i += 256) {
            int m = i / 16, k = i % 16;
            int r = row0 + m;
            As[k][m] = (r < N_NODES) ? h[(size_t)r * IN_F + k0 + k] : 0.f;
        }
        for (int i = tid; i < 16 * 64; i += 256) {
            int k = i / 64, n = i % 64;
            Bs[k][n] = W[(size_t)(k0 + k) * D_DIM + col0 + n];
        }
        __syncthreads();
        #pragma unroll
        for (int k = 0; k < 16; ++k) {
            float a[4], b[4];
            #pragma unroll
            for (int i = 0; i < 4; i++) a[i] = As[k][tm * 4 + i];
            #pragma unroll
            for (int j = 0; j < 4; j++) b[j] = Bs[k][tn * 4 + j];
            #pragma unroll
            for (int i = 0; i < 4; i++)
                #pragma unroll
                for (int j = 0; j < 4; j++)
                    acc[i][j] += a[i] * b[j];
        }
        __syncthreads();
    }
    #pragma unroll
    for (int i = 0; i < 4; i++) {
        int r = row0 + tm * 4 + i;
        if (r < N_NODES) {
            unsigned* p = featb + (size_t)r * (D_DIM / 2) + (col0 >> 1) + tn * 2;
            p[0] = pk_bf16(acc[i][0], acc[i][1]);
            p[1] = pk_bf16(acc[i][2], acc[i][3]);
        }
    }
}

// ------- el/er: per (node, head) dot with attn vectors (bf16 feat) -------
__global__ void attn_dots(const unsigned* __restrict__ featb,
                          const float* __restrict__ al,
                          const float* __restrict__ ar,
                          float* __restrict__ el, float* __restrict__ er) {
    int idx = blockIdx.x * blockDim.x + threadIdx.x;   // n*H + h
    if (idx >= N_NODES * H_HEADS) return;
    int n = idx / H_HEADS, hh = idx % H_HEADS;
    const uint4* fv = (const uint4*)(featb + (size_t)n * (D_DIM / 2) + hh * (O_DIM / 2));
    const float* a = al + hh * O_DIM;
    const float* b = ar + hh * O_DIM;
    float sl = 0.f, sr = 0.f;
    #pragma unroll
    for (int q = 0; q < 4; q++) {
        uint4 v = fv[q];
        unsigned ws[4] = {v.x, v.y, v.z, v.w};
        #pragma unroll
        for (int k = 0; k < 4; k++) {
            int o = q * 8 + k * 2;
            float f0 = bflo(ws[k]), f1 = bfhi(ws[k]);
            sl += f0 * a[o] + f1 * a[o + 1];
            sr += f0 * b[o] + f1 * b[o + 1];
        }
    }
    el[idx] = sl; er[idx] = sr;
}

// ------- CSR build -------
__global__ void count_deg(const int* __restrict__ dst, int* __restrict__ deg) {
    int e = blockIdx.x * blockDim.x + threadIdx.x;
    if (e < E_EDGES) atomicAdd(&deg[dst[e]], 1);
}

#define SCAN_T 1024
__global__ __launch_bounds__(SCAN_T) void exscan_deg(const int* __restrict__ deg,
                                                     int* __restrict__ rowptr) {
    __shared__ int part[SCAN_T];
    const int t = threadIdx.x;
    const int CH = (N_NODES + SCAN_T - 1) / SCAN_T;
    const int base = t * CH;
    int sum = 0;
    for (int i = 0; i < CH; i++) {
        int idx = base + i;
        if (idx < N_NODES) sum += deg[idx];
    }
    part[t] = sum;
    __syncthreads();
    for (int off = 1; off < SCAN_T; off <<= 1) {
        int v = (t >= off) ? part[t - off] : 0;
        __syncthreads();
        part[t] += v;
        __syncthreads();
    }
    int run = (t == 0) ? 0 : part[t - 1];
    for (int i = 0; i < CH; i++) {
        int idx = base + i;
        if (idx < N_NODES) { rowptr[idx] = run; run += deg[idx]; }
    }
    if (t == SCAN_T - 1) rowptr[N_NODES] = part[SCAN_T - 1];
}

__global__ void fill_bucket(const int* __restrict__ src, const int* __restrict__ dst,
                            const int* __restrict__ rowptr, int* __restrict__ cursor,
                            int* __restrict__ bsrc) {
    int e = blockIdx.x * blockDim.x + threadIdx.x;
    if (e >= E_EDGES) return;
    int d = dst[e];
    int j = rowptr[d] + atomicAdd(&cursor[d], 1);
    bsrc[j] = src[e];
}

// ------- gather: single pass, den + numerator together; bf16 feat; 2 comps/thread -------
__global__ __launch_bounds__(128) void gather_z(const int* __restrict__ rowptr,
                                                const int* __restrict__ bsrc,
                                                const float* __restrict__ el,
                                                const float* __restrict__ er,
                                                const unsigned* __restrict__ featb,
                                                const float* __restrict__ bias,
                                                float* __restrict__ z) {
    const int d = blockIdx.x;
    const int t = threadIdx.x;          // component pair index (0..127)
    const int hh = t >> 4;              // head
    const int j0 = rowptr[d], j1 = rowptr[d + 1];
    const float erd = er[d * H_HEADS + hh];

    float den = 0.f, a0 = 0.f, a1 = 0.f;
    for (int j = j0; j < j1; ++j) {
        int s = bsrc[j];
        float x = el[s * H_HEADS + hh] + erd;
        x = x > 0.f ? x : NEG_SLOPE * x;
        float ex = expf(x);
        unsigned w = featb[(size_t)s * (D_DIM / 2) + t];
        den += ex;
        a0 += ex * bflo(w);
        a1 += ex * bfhi(w);
    }
    float inv = 1.f / (den == 0.f ? 1.f : den);
    float x0 = a0 * inv + bias[2 * t];
    float x1 = a1 * inv + bias[2 * t + 1];
    float2 r;
    r.x = x0 > 0.f ? x0 : expm1f(x0);
    r.y = x1 > 0.f ? x1 : expm1f(x1);
    ((float2*)(z + (size_t)d * D_DIM))[t] = r;
}

// ------- semantic attention: accumulate sum_n w[n,m] -------
#define ROWS_PER_BLK 16
__global__ __launch_bounds__(128) void semantic_w(const float* __restrict__ z,
                                                  const float* __restrict__ W1,
                                                  const float* __restrict__ b1,
                                                  const float* __restrict__ W2,
                                                  float* __restrict__ wsum) {
    __shared__ float zs[ROWS_PER_BLK][D_DIM];
    __shared__ float red[128];
    const int t = threadIdx.x;
    const size_t r0 = (size_t)blockIdx.x * ROWS_PER_BLK;
    const int m = (int)(r0 / N_NODES);

    for (int i = t; i < ROWS_PER_BLK * D_DIM; i += 128) {
        int rr = i / D_DIM;
        zs[rr][i % D_DIM] = z[(r0 + rr) * D_DIM + (i % D_DIM)];
    }
    __syncthreads();

    float acc[ROWS_PER_BLK];
    float bb = b1[t];
    #pragma unroll
    for (int rr = 0; rr < ROWS_PER_BLK; rr++) acc[rr] = bb;
    for (int d = 0; d < D_DIM; d++) {
        float w = W1[(size_t)d * HID_DIM + t];
        #pragma unroll
        for (int rr = 0; rr < ROWS_PER_BLK; rr++) acc[rr] += zs[rr][d] * w;
    }
    float w2 = W2[t];
    float part = 0.f;
    #pragma unroll
    for (int rr = 0; rr < ROWS_PER_BLK; rr++) part += tanhf(acc[rr]) * w2;

    red[t] = part;
    __syncthreads();
    for (int s = 64; s > 0; s >>= 1) {
        if (t < s) red[t] += red[t + s];
        __syncthreads();
    }
    if (t == 0) atomicAdd(&wsum[m], red[0]);
}

__global__ void compute_beta(const float* __restrict__ wsum, float* __restrict__ beta) {
    float w0 = wsum[0] / N_NODES, w1 = wsum[1] / N_NODES, w2 = wsum[2] / N_NODES;
    float mx = fmaxf(w0, fmaxf(w1, w2));
    float e0 = expf(w0 - mx), e1 = expf(w1 - mx), e2 = expf(w2 - mx);
    float s = e0 + e1 + e2;
    beta[0] = e0 / s; beta[1] = e1 / s; beta[2] = e2 / s;
}

__global__ void final_mix(const float* __restrict__ z, const float* __restrict__ beta,
                          float* __restrict__ out) {
    int i = blockIdx.x * blockDim.x + threadIdx.x;
    if (i >= N_NODES * D_DIM) return;
    const size_t stride = (size_t)N_NODES * D_DIM;
    out[i] = beta[0] * z[i] + beta[1] * z[stride + i] + beta[2] * z[2 * stride + i];
}

extern "C" void kernel_launch(void* const* d_in, const int* in_sizes, int n_in,
                              void* d_out, int out_size, void* d_ws, size_t ws_size,
                              hipStream_t stream) {
    const float* h        = (const float*)d_in[0];
    const int*   eidx     = (const int*)d_in[1];
    const float* W        = (const float*)d_in[2];
    const float* attn_l   = (const float*)d_in[3];
    const float* attn_r   = (const float*)d_in[4];
    const float* bias     = (const float*)d_in[5];
    const float* sem_W1   = (const float*)d_in[6];
    const float* sem_b1   = (const float*)d_in[7];
    const float* sem_W2   = (const float*)d_in[8];
    float* out = (float*)d_out;

    float*    ws    = (float*)d_ws;
    float*    z     = ws;                                       // M*N*D fp32   153.6 MB
    unsigned* featb = (unsigned*)(z + (size_t)M_PATHS * N_NODES * D_DIM); // N*D/2 u32  25.6 MB
    float*    el    = (float*)(featb + (size_t)N_NODES * (D_DIM / 2));    // N*H
    float*    er    = el + N_NODES * H_HEADS;
    float*    wsum  = er + N_NODES * H_HEADS;                   // 8
    float*    beta  = wsum + 8;                                 // 8
    int*      bsrc  = (int*)(beta + 8);                         // E
    int*      rowptr= bsrc + E_EDGES;                           // N+1
    int*      deg   = rowptr + N_NODES + 1;                     // N
    int*      cursor= deg + N_NODES;                            // N

    hipMemsetAsync(wsum, 0, 16 * sizeof(float), stream);

    for (int m = 0; m < M_PATHS; ++m) {
        const float* hm  = h + (size_t)m * N_NODES * IN_F;
        const float* Wm  = W + (size_t)m * IN_F * D_DIM;
        const int*   src = eidx + (size_t)m * 2 * E_EDGES;
        const int*   dst = src + E_EDGES;
        float*       zm  = z + (size_t)m * N_NODES * D_DIM;

        hipMemsetAsync(deg, 0, 2 * N_NODES * sizeof(int), stream);  // deg + cursor

        dim3 g1((N_NODES + 63) / 64, D_DIM / 64);
        gemm_feat<<<g1, 256, 0, stream>>>(hm, Wm, featb);

        attn_dots<<<(N_NODES * H_HEADS + 255) / 256, 256, 0, stream>>>(
            featb, attn_l + m * H_HEADS * O_DIM, attn_r + m * H_HEADS * O_DIM, el, er);

        count_deg<<<(E_EDGES + 255) / 256, 256, 0, stream>>>(dst, deg);
        exscan_deg<<<1, SCAN_T, 0, stream>>>(deg, rowptr);
        fill_bucket<<<(E_EDGES + 255) / 256, 256, 0, stream>>>(src, dst, rowptr, cursor, bsrc);

        gather_z<<<N_NODES, 128, 0, stream>>>(rowptr, bsrc, el, er, featb,
                                              bias + m * D_DIM, zm);
    }

    semantic_w<<<M_PATHS * N_NODES / ROWS_PER_BLK, 128, 0, stream>>>(
        z, sem_W1, sem_b1, sem_W2, wsum);
    compute_beta<<<1, 1, 0, stream>>>(wsum, beta);
    final_mix<<<(N_NODES * D_DIM + 255) / 256, 256, 0, stream>>>(z, beta, out);
}

// Round 4
// 1287.383 us; speedup vs baseline: 2.1461x; 1.0890x over previous
//
#include <hip/hip_runtime.h>
#include <hip/hip_bf16.h>
#include <math.h>
#include <string.h>

#define N_NODES 50000
#define E_EDGES 800000
#define M_PATHS 3
#define IN_F    128
#define H_HEADS 8
#define O_DIM   32
#define D_DIM   256   // H*O
#define HID_DIM 128
#define NEG_SLOPE 0.2f

typedef __attribute__((ext_vector_type(8))) short bf16x8;
typedef __attribute__((ext_vector_type(4))) float f32x4;

__device__ __forceinline__ float bflo(unsigned w) { return __uint_as_float(w << 16); }
__device__ __forceinline__ float bfhi(unsigned w) { return __uint_as_float(w & 0xffff0000u); }

__device__ __forceinline__ unsigned short f2bf(float f) {
    __hip_bfloat16 hb = __float2bfloat16(f);
    unsigned short us;
    memcpy(&us, &hb, 2);
    return us;
}

// load 8 consecutive fp32, convert to packed bf16x8 fragment
__device__ __forceinline__ bf16x8 cvt_frag(const float* __restrict__ p) {
    union { unsigned short u[8]; bf16x8 v; } r;
    const float4 f0 = *reinterpret_cast<const float4*>(p);
    const float4 f1 = *reinterpret_cast<const float4*>(p + 4);
    r.u[0] = f2bf(f0.x); r.u[1] = f2bf(f0.y); r.u[2] = f2bf(f0.z); r.u[3] = f2bf(f0.w);
    r.u[4] = f2bf(f1.x); r.u[5] = f2bf(f1.y); r.u[6] = f2bf(f1.z); r.u[7] = f2bf(f1.w);
    return r.v;
}
__device__ __forceinline__ bf16x8 zero_frag() {
    union { unsigned short u[8]; bf16x8 v; } r = {};
    return r.v;
}

// ------- transpose-convert: in [K][C] fp32 -> out [C][K] bf16 -------
__global__ void transpose_bf16(const float* __restrict__ in, unsigned short* __restrict__ out,
                               int K, int C) {
    int i = blockIdx.x * blockDim.x + threadIdx.x;
    if (i >= K * C) return;
    int k = i / C, c = i % C;
    out[(size_t)c * K + k] = f2bf(in[i]);
}

// ------- GEMM: featb(bf16) = h @ W via MFMA; A=h fp32 on-the-fly, B=Wt bf16 [256][128] -------
__global__ __launch_bounds__(256) void gemm_feat_mfma(const float* __restrict__ h,
                                                      const unsigned short* __restrict__ Wt,
                                                      unsigned short* __restrict__ featb) {
    const int wave = threadIdx.x >> 6;
    const int lane = threadIdx.x & 63;
    const int l15 = lane & 15, lhi = lane >> 4;
    const int r0 = blockIdx.x * 64;     // row tile
    const int c0 = wave * 64;           // col tile (4 waves cover 256)
    f32x4 acc[4][4] = {};

    for (int ks = 0; ks < 4; ++ks) {    // K = 128, step 32
        bf16x8 a[4], b[4];
        #pragma unroll
        for (int rg = 0; rg < 4; rg++) {
            int row = r0 + rg * 16 + l15;
            a[rg] = (row < N_NODES) ? cvt_frag(h + (size_t)row * IN_F + ks * 32 + lhi * 8)
                                    : zero_frag();
        }
        #pragma unroll
        for (int ct = 0; ct < 4; ct++) {
            int col = c0 + ct * 16 + l15;
            b[ct] = *reinterpret_cast<const bf16x8*>(Wt + (size_t)col * IN_F + ks * 32 + lhi * 8);
        }
        #pragma unroll
        for (int rg = 0; rg < 4; rg++)
            #pragma unroll
            for (int ct = 0; ct < 4; ct++)
                acc[rg][ct] = __builtin_amdgcn_mfma_f32_16x16x32_bf16(a[rg], b[ct], acc[rg][ct], 0, 0, 0);
    }
    #pragma unroll
    for (int rg = 0; rg < 4; rg++) {
        #pragma unroll
        for (int reg = 0; reg < 4; reg++) {
            int row = r0 + rg * 16 + lhi * 4 + reg;
            if (row < N_NODES) {
                #pragma unroll
                for (int ct = 0; ct < 4; ct++) {
                    int col = c0 + ct * 16 + l15;
                    featb[(size_t)row * D_DIM + col] = f2bf(acc[rg][ct][reg]);
                }
            }
        }
    }
}

// ------- el/er: per (node, head) dot with attn vectors (bf16 feat) -------
__global__ void attn_dots(const unsigned* __restrict__ featb,
                          const float* __restrict__ al,
                          const float* __restrict__ ar,
                          float* __restrict__ el, float* __restrict__ er) {
    int idx = blockIdx.x * blockDim.x + threadIdx.x;   // n*H + h
    if (idx >= N_NODES * H_HEADS) return;
    int n = idx / H_HEADS, hh = idx % H_HEADS;
    const uint4* fv = (const uint4*)(featb + (size_t)n * (D_DIM / 2) + hh * (O_DIM / 2));
    const float* a = al + hh * O_DIM;
    const float* b = ar + hh * O_DIM;
    float sl = 0.f, sr = 0.f;
    #pragma unroll
    for (int q = 0; q < 4; q++) {
        uint4 v = fv[q];
        unsigned ws4[4] = {v.x, v.y, v.z, v.w};
        #pragma unroll
        for (int k = 0; k < 4; k++) {
            int o = q * 8 + k * 2;
            float f0 = bflo(ws4[k]), f1 = bfhi(ws4[k]);
            sl += f0 * a[o] + f1 * a[o + 1];
            sr += f0 * b[o] + f1 * b[o + 1];
        }
    }
    el[idx] = sl; er[idx] = sr;
}

// ------- CSR build -------
__global__ void count_deg(const int* __restrict__ dst, int* __restrict__ deg) {
    int e = blockIdx.x * blockDim.x + threadIdx.x;
    if (e < E_EDGES) atomicAdd(&deg[dst[e]], 1);
}

#define SCAN_T 1024
__global__ __launch_bounds__(SCAN_T) void exscan_deg(const int* __restrict__ deg,
                                                     int* __restrict__ rowptr) {
    __shared__ int part[SCAN_T];
    const int t = threadIdx.x;
    const int CH = (N_NODES + SCAN_T - 1) / SCAN_T;
    const int base = t * CH;
    int sum = 0;
    for (int i = 0; i < CH; i++) {
        int idx = base + i;
        if (idx < N_NODES) sum += deg[idx];
    }
    part[t] = sum;
    __syncthreads();
    for (int off = 1; off < SCAN_T; off <<= 1) {
        int v = (t >= off) ? part[t - off] : 0;
        __syncthreads();
        part[t] += v;
        __syncthreads();
    }
    int run = (t == 0) ? 0 : part[t - 1];
    for (int i = 0; i < CH; i++) {
        int idx = base + i;
        if (idx < N_NODES) { rowptr[idx] = run; run += deg[idx]; }
    }
    if (t == SCAN_T - 1) rowptr[N_NODES] = part[SCAN_T - 1];
}

__global__ void fill_bucket(const int* __restrict__ src, const int* __restrict__ dst,
                            const int* __restrict__ rowptr, int* __restrict__ cursor,
                            int* __restrict__ bsrc) {
    int e = blockIdx.x * blockDim.x + threadIdx.x;
    if (e >= E_EDGES) return;
    int d = dst[e];
    int j = rowptr[d] + atomicAdd(&cursor[d], 1);
    bsrc[j] = src[e];
}

// ------- gather: single pass, den + numerator together; bf16 feat; 2 comps/thread -------
__global__ __launch_bounds__(128) void gather_z(const int* __restrict__ rowptr,
                                                const int* __restrict__ bsrc,
                                                const float* __restrict__ el,
                                                const float* __restrict__ er,
                                                const unsigned* __restrict__ featb,
                                                const float* __restrict__ bias,
                                                float* __restrict__ z) {
    const int d = blockIdx.x;
    const int t = threadIdx.x;          // component pair index (0..127)
    const int hh = t >> 4;              // head
    const int j0 = rowptr[d], j1 = rowptr[d + 1];
    const float erd = er[d * H_HEADS + hh];

    float den = 0.f, a0 = 0.f, a1 = 0.f;
    for (int j = j0; j < j1; ++j) {
        int s = bsrc[j];
        float x = el[s * H_HEADS + hh] + erd;
        x = x > 0.f ? x : NEG_SLOPE * x;
        float ex = expf(x);
        unsigned w = featb[(size_t)s * (D_DIM / 2) + t];
        den += ex;
        a0 += ex * bflo(w);
        a1 += ex * bfhi(w);
    }
    float inv = 1.f / (den == 0.f ? 1.f : den);
    float x0 = a0 * inv + bias[2 * t];
    float x1 = a1 * inv + bias[2 * t + 1];
    float2 r;
    r.x = x0 > 0.f ? x0 : expm1f(x0);
    r.y = x1 > 0.f ? x1 : expm1f(x1);
    ((float2*)(z + (size_t)d * D_DIM))[t] = r;
}

// ------- semantic attention via MFMA: wsum[m] += sum_rows tanh(z@W1+b1)@W2 -------
__global__ __launch_bounds__(256) void semantic_mfma(const float* __restrict__ z,
                                                     const unsigned short* __restrict__ W1t,
                                                     const float* __restrict__ b1,
                                                     const float* __restrict__ W2,
                                                     float* __restrict__ wsum, int m) {
    const int wave = threadIdx.x >> 6;
    const int lane = threadIdx.x & 63;
    const int l15 = lane & 15, lhi = lane >> 4;
    const int r0 = blockIdx.x * 64 + wave * 16;   // 16 rows per wave
    f32x4 acc[8] = {};

    for (int ks = 0; ks < 8; ++ks) {              // K = 256, step 32
        int row = r0 + l15;
        bf16x8 a = (row < N_NODES) ? cvt_frag(z + (size_t)row * D_DIM + ks * 32 + lhi * 8)
                                   : zero_frag();
        #pragma unroll
        for (int ht = 0; ht < 8; ht++) {
            int col = ht * 16 + l15;
            bf16x8 b = *reinterpret_cast<const bf16x8*>(W1t + (size_t)col * D_DIM + ks * 32 + lhi * 8);
            acc[ht] = __builtin_amdgcn_mfma_f32_16x16x32_bf16(a, b, acc[ht], 0, 0, 0);
        }
    }
    float part = 0.f;
    #pragma unroll
    for (int ht = 0; ht < 8; ht++) {
        int col = ht * 16 + l15;
        float bb = b1[col], w2 = W2[col];
        #pragma unroll
        for (int reg = 0; reg < 4; reg++) {
            int row = r0 + lhi * 4 + reg;
            if (row < N_NODES) part += tanhf(acc[ht][reg] + bb) * w2;
        }
    }
    #pragma unroll
    for (int off = 1; off < 64; off <<= 1) part += __shfl_xor(part, off);
    if (lane == 0) atomicAdd(&wsum[m], part);
}

__global__ void compute_beta(const float* __restrict__ wsum, float* __restrict__ beta) {
    float w0 = wsum[0] / N_NODES, w1 = wsum[1] / N_NODES, w2 = wsum[2] / N_NODES;
    float mx = fmaxf(w0, fmaxf(w1, w2));
    float e0 = expf(w0 - mx), e1 = expf(w1 - mx), e2 = expf(w2 - mx);
    float s = e0 + e1 + e2;
    beta[0] = e0 / s; beta[1] = e1 / s; beta[2] = e2 / s;
}

__global__ void final_mix(const float* __restrict__ z, const float* __restrict__ beta,
                          float* __restrict__ out) {
    int i = blockIdx.x * blockDim.x + threadIdx.x;
    if (i >= N_NODES * D_DIM) return;
    const size_t stride = (size_t)N_NODES * D_DIM;
    out[i] = beta[0] * z[i] + beta[1] * z[stride + i] + beta[2] * z[2 * stride + i];
}

extern "C" void kernel_launch(void* const* d_in, const int* in_sizes, int n_in,
                              void* d_out, int out_size, void* d_ws, size_t ws_size,
                              hipStream_t stream) {
    const float* h        = (const float*)d_in[0];
    const int*   eidx     = (const int*)d_in[1];
    const float* W        = (const float*)d_in[2];
    const float* attn_l   = (const float*)d_in[3];
    const float* attn_r   = (const float*)d_in[4];
    const float* bias     = (const float*)d_in[5];
    const float* sem_W1   = (const float*)d_in[6];
    const float* sem_b1   = (const float*)d_in[7];
    const float* sem_W2   = (const float*)d_in[8];
    float* out = (float*)d_out;

    float* ws = (float*)d_ws;
    float* z    = ws;                                      // M*N*D fp32  153.6 MB
    float* el   = z + (size_t)M_PATHS * N_NODES * D_DIM;   // N*H
    float* er   = el + N_NODES * H_HEADS;                  // N*H
    float* wsum = er + N_NODES * H_HEADS;                  // 8
    float* beta = wsum + 8;                                // 8
    unsigned short* featb = (unsigned short*)(beta + 8);   // N*D bf16    25.6 MB
    unsigned short* Wt    = featb + (size_t)N_NODES * D_DIM;   // M*D*IN bf16
    unsigned short* W1t   = Wt + (size_t)M_PATHS * D_DIM * IN_F; // HID*D bf16
    int* bsrc   = (int*)(W1t + (size_t)HID_DIM * D_DIM);   // E
    int* rowptr = bsrc + E_EDGES;                          // N+1
    int* deg    = rowptr + N_NODES + 1;                    // N
    int* cursor = deg + N_NODES;                           // N

    hipMemsetAsync(wsum, 0, 16 * sizeof(float), stream);

    // one-time weight prep: W[m] -> Wt[m] (bf16, [D][IN]); W1 -> W1t (bf16, [HID][D])
    for (int m = 0; m < M_PATHS; ++m)
        transpose_bf16<<<(IN_F * D_DIM + 255) / 256, 256, 0, stream>>>(
            W + (size_t)m * IN_F * D_DIM, Wt + (size_t)m * D_DIM * IN_F, IN_F, D_DIM);
    transpose_bf16<<<(D_DIM * HID_DIM + 255) / 256, 256, 0, stream>>>(
        sem_W1, W1t, D_DIM, HID_DIM);

    for (int m = 0; m < M_PATHS; ++m) {
        const float* hm  = h + (size_t)m * N_NODES * IN_F;
        const int*   src = eidx + (size_t)m * 2 * E_EDGES;
        const int*   dst = src + E_EDGES;
        float*       zm  = z + (size_t)m * N_NODES * D_DIM;

        hipMemsetAsync(deg, 0, 2 * N_NODES * sizeof(int), stream);  // deg + cursor

        gemm_feat_mfma<<<(N_NODES + 63) / 64, 256, 0, stream>>>(
            hm, Wt + (size_t)m * D_DIM * IN_F, featb);

        attn_dots<<<(N_NODES * H_HEADS + 255) / 256, 256, 0, stream>>>(
            (const unsigned*)featb, attn_l + m * H_HEADS * O_DIM,
            attn_r + m * H_HEADS * O_DIM, el, er);

        count_deg<<<(E_EDGES + 255) / 256, 256, 0, stream>>>(dst, deg);
        exscan_deg<<<1, SCAN_T, 0, stream>>>(deg, rowptr);
        fill_bucket<<<(E_EDGES + 255) / 256, 256, 0, stream>>>(src, dst, rowptr, cursor, bsrc);

        gather_z<<<N_NODES, 128, 0, stream>>>(rowptr, bsrc, el, er,
                                              (const unsigned*)featb, bias + m * D_DIM, zm);
    }

    for (int m = 0; m < M_PATHS; ++m)
        semantic_mfma<<<(N_NODES + 63) / 64, 256, 0, stream>>>(
            z + (size_t)m * N_NODES * D_DIM, W1t, sem_b1, sem_W2, wsum, m);
    compute_beta<<<1, 1, 0, stream>>>(wsum, beta);
    final_mix<<<(N_NODES * D_DIM + 255) / 256, 256, 0, stream>>>(z, beta, out);
}

// Round 5
// 1013.609 us; speedup vs baseline: 2.7257x; 1.2701x over previous
//
#include <hip/hip_runtime.h>
#include <hip/hip_bf16.h>
#include <math.h>
#include <string.h>

#define N_NODES 50000
#define E_EDGES 800000
#define M_PATHS 3
#define IN_F    128
#define H_HEADS 8
#define O_DIM   32
#define D_DIM   256   // H*O
#define HID_DIM 128
#define NEG_SLOPE 0.2f

typedef __attribute__((ext_vector_type(8))) short bf16x8;
typedef __attribute__((ext_vector_type(4))) float f32x4;

__device__ __forceinline__ float bflo(unsigned w) { return __uint_as_float(w << 16); }
__device__ __forceinline__ float bfhi(unsigned w) { return __uint_as_float(w & 0xffff0000u); }

__device__ __forceinline__ unsigned short f2bf(float f) {
    __hip_bfloat16 hb = __float2bfloat16(f);
    unsigned short us;
    memcpy(&us, &hb, 2);
    return us;
}
__device__ __forceinline__ unsigned pk_bf16(float a, float b) {
    return (unsigned)f2bf(a) | ((unsigned)f2bf(b) << 16);
}

// load 8 consecutive fp32, convert to packed bf16x8 fragment
__device__ __forceinline__ bf16x8 cvt_frag(const float* __restrict__ p) {
    union { unsigned short u[8]; bf16x8 v; } r;
    const float4 f0 = *reinterpret_cast<const float4*>(p);
    const float4 f1 = *reinterpret_cast<const float4*>(p + 4);
    r.u[0] = f2bf(f0.x); r.u[1] = f2bf(f0.y); r.u[2] = f2bf(f0.z); r.u[3] = f2bf(f0.w);
    r.u[4] = f2bf(f1.x); r.u[5] = f2bf(f1.y); r.u[6] = f2bf(f1.z); r.u[7] = f2bf(f1.w);
    return r.v;
}
__device__ __forceinline__ bf16x8 zero_frag() {
    union { unsigned short u[8]; bf16x8 v; } r = {};
    return r.v;
}

// ------- batched transpose-convert: W[m] [K][C] fp32 -> Wt[m] [C][K] bf16 -------
__global__ void transpose_w(const float* __restrict__ in, unsigned short* __restrict__ out,
                            int K, int C) {
    const int m = blockIdx.y;
    int i = blockIdx.x * blockDim.x + threadIdx.x;
    if (i >= K * C) return;
    int k = i / C, c = i % C;
    out[(size_t)m * K * C + (size_t)c * K + k] = f2bf(in[(size_t)m * K * C + i]);
}

// ------- GEMM: featb(bf16) = h @ W via MFMA; A=h fp32 on-the-fly, B=Wt bf16 [256][128] -------
__global__ __launch_bounds__(256) void gemm_feat_mfma(const float* __restrict__ h,
                                                      const unsigned short* __restrict__ Wt,
                                                      unsigned short* __restrict__ featb) {
    const int wave = threadIdx.x >> 6;
    const int lane = threadIdx.x & 63;
    const int l15 = lane & 15, lhi = lane >> 4;
    const int r0 = blockIdx.x * 64;     // row tile
    const int c0 = wave * 64;           // col tile (4 waves cover 256)
    f32x4 acc[4][4] = {};

    for (int ks = 0; ks < 4; ++ks) {    // K = 128, step 32
        bf16x8 a[4], b[4];
        #pragma unroll
        for (int rg = 0; rg < 4; rg++) {
            int row = r0 + rg * 16 + l15;
            a[rg] = (row < N_NODES) ? cvt_frag(h + (size_t)row * IN_F + ks * 32 + lhi * 8)
                                    : zero_frag();
        }
        #pragma unroll
        for (int ct = 0; ct < 4; ct++) {
            int col = c0 + ct * 16 + l15;
            b[ct] = *reinterpret_cast<const bf16x8*>(Wt + (size_t)col * IN_F + ks * 32 + lhi * 8);
        }
        #pragma unroll
        for (int rg = 0; rg < 4; rg++)
            #pragma unroll
            for (int ct = 0; ct < 4; ct++)
                acc[rg][ct] = __builtin_amdgcn_mfma_f32_16x16x32_bf16(a[rg], b[ct], acc[rg][ct], 0, 0, 0);
    }
    #pragma unroll
    for (int rg = 0; rg < 4; rg++) {
        #pragma unroll
        for (int reg = 0; reg < 4; reg++) {
            int row = r0 + rg * 16 + lhi * 4 + reg;
            if (row < N_NODES) {
                #pragma unroll
                for (int ct = 0; ct < 4; ct++) {
                    int col = c0 + ct * 16 + l15;
                    featb[(size_t)row * D_DIM + col] = f2bf(acc[rg][ct][reg]);
                }
            }
        }
    }
}

// ------- el/er: per (node, head) dot with attn vectors (bf16 feat) -------
__global__ void attn_dots(const unsigned* __restrict__ featb,
                          const float* __restrict__ al,
                          const float* __restrict__ ar,
                          float* __restrict__ el, float* __restrict__ er) {
    int idx = blockIdx.x * blockDim.x + threadIdx.x;   // n*H + h
    if (idx >= N_NODES * H_HEADS) return;
    int n = idx / H_HEADS, hh = idx % H_HEADS;
    const uint4* fv = (const uint4*)(featb + (size_t)n * (D_DIM / 2) + hh * (O_DIM / 2));
    const float* a = al + hh * O_DIM;
    const float* b = ar + hh * O_DIM;
    float sl = 0.f, sr = 0.f;
    #pragma unroll
    for (int q = 0; q < 4; q++) {
        uint4 v = fv[q];
        unsigned ws4[4] = {v.x, v.y, v.z, v.w};
        #pragma unroll
        for (int k = 0; k < 4; k++) {
            int o = q * 8 + k * 2;
            float f0 = bflo(ws4[k]), f1 = bfhi(ws4[k]);
            sl += f0 * a[o] + f1 * a[o + 1];
            sr += f0 * b[o] + f1 * b[o + 1];
        }
    }
    el[idx] = sl; er[idx] = sr;
}

// ------- batched CSR build -------
__global__ void count_all(const int* __restrict__ eidx, int* __restrict__ deg3) {
    const int m = blockIdx.y;
    int e = blockIdx.x * blockDim.x + threadIdx.x;
    if (e >= E_EDGES) return;
    const int* dst = eidx + (size_t)m * 2 * E_EDGES + E_EDGES;
    atomicAdd(&deg3[m * N_NODES + dst[e]], 1);
}

#define SCAN_T 1024
__global__ __launch_bounds__(SCAN_T) void exscan_all(const int* __restrict__ deg3,
                                                     int* __restrict__ rowptr3) {
    __shared__ int part[SCAN_T];
    const int m = blockIdx.x;
    const int* deg = deg3 + m * N_NODES;
    int* rowptr = rowptr3 + m * (N_NODES + 1);
    const int t = threadIdx.x;
    const int CH = (N_NODES + SCAN_T - 1) / SCAN_T;
    const int base = t * CH;
    int sum = 0;
    for (int i = 0; i < CH; i++) {
        int idx = base + i;
        if (idx < N_NODES) sum += deg[idx];
    }
    part[t] = sum;
    __syncthreads();
    for (int off = 1; off < SCAN_T; off <<= 1) {
        int v = (t >= off) ? part[t - off] : 0;
        __syncthreads();
        part[t] += v;
        __syncthreads();
    }
    int run = (t == 0) ? 0 : part[t - 1];
    for (int i = 0; i < CH; i++) {
        int idx = base + i;
        if (idx < N_NODES) { rowptr[idx] = run; run += deg[idx]; }
    }
    if (t == SCAN_T - 1) rowptr[N_NODES] = part[SCAN_T - 1];
}

__global__ void fill_all(const int* __restrict__ eidx, const int* __restrict__ rowptr3,
                         int* __restrict__ cursor3, int* __restrict__ bsrc3) {
    const int m = blockIdx.y;
    int e = blockIdx.x * blockDim.x + threadIdx.x;
    if (e >= E_EDGES) return;
    const int* src = eidx + (size_t)m * 2 * E_EDGES;
    const int* dst = src + E_EDGES;
    int d = dst[e];
    int j = rowptr3[m * (N_NODES + 1) + d] + atomicAdd(&cursor3[m * N_NODES + d], 1);
    bsrc3[(size_t)m * E_EDGES + j] = src[e];
}

// ------- gather: 1 wave per node, 4 comps/lane, shfl-broadcast softmax; bf16 z out -------
__global__ __launch_bounds__(128) void gather_z(const int* __restrict__ rowptr,
                                                const int* __restrict__ bsrc,
                                                const float* __restrict__ el,
                                                const float* __restrict__ er,
                                                const uint2* __restrict__ featb2,
                                                const float* __restrict__ bias,
                                                uint2* __restrict__ zb2) {
    const int wid = threadIdx.x >> 6;
    const int l = threadIdx.x & 63;
    const int d = blockIdx.x * 2 + wid;
    const int vh = l & 7;               // virtual head this lane evaluates exp for
    const int hh = l >> 3;              // head this lane's components belong to
    const int j0 = rowptr[d], j1 = rowptr[d + 1];
    const float erv = er[d * H_HEADS + vh];

    float den = 0.f, a0 = 0.f, a1 = 0.f, a2 = 0.f, a3 = 0.f;
    for (int j = j0; j < j1; ++j) {
        int s = bsrc[j];
        float x = el[s * H_HEADS + vh] + erv;
        x = fmaxf(x, NEG_SLOPE * x);            // leaky_relu
        float exv = __expf(x);
        float ex = __shfl(exv, hh);             // broadcast head hh's exp
        uint2 w = featb2[(size_t)s * 64 + l];
        den += ex;
        a0 += ex * bflo(w.x); a1 += ex * bfhi(w.x);
        a2 += ex * bflo(w.y); a3 += ex * bfhi(w.y);
    }
    float inv = 1.f / (den == 0.f ? 1.f : den);
    float4 b4 = ((const float4*)bias)[l];
    float x0 = a0 * inv + b4.x;
    float x1 = a1 * inv + b4.y;
    float x2 = a2 * inv + b4.z;
    float x3 = a3 * inv + b4.w;
    x0 = x0 > 0.f ? x0 : expm1f(x0);
    x1 = x1 > 0.f ? x1 : expm1f(x1);
    x2 = x2 > 0.f ? x2 : expm1f(x2);
    x3 = x3 > 0.f ? x3 : expm1f(x3);
    uint2 r;
    r.x = pk_bf16(x0, x1);
    r.y = pk_bf16(x2, x3);
    zb2[(size_t)d * 64 + l] = r;
}

// ------- semantic attention via MFMA on bf16 z: wsum[m] += sum_rows tanh(z@W1+b1)@W2 -------
__global__ __launch_bounds__(256) void semantic_mfma(const unsigned short* __restrict__ zb,
                                                     const unsigned short* __restrict__ W1t,
                                                     const float* __restrict__ b1,
                                                     const float* __restrict__ W2,
                                                     float* __restrict__ wsum, int m) {
    const int wave = threadIdx.x >> 6;
    const int lane = threadIdx.x & 63;
    const int l15 = lane & 15, lhi = lane >> 4;
    const int r0 = blockIdx.x * 64 + wave * 16;   // 16 rows per wave
    f32x4 acc[8] = {};

    for (int ks = 0; ks < 8; ++ks) {              // K = 256, step 32
        int row = r0 + l15;
        bf16x8 a = (row < N_NODES)
            ? *reinterpret_cast<const bf16x8*>(zb + (size_t)row * D_DIM + ks * 32 + lhi * 8)
            : zero_frag();
        #pragma unroll
        for (int ht = 0; ht < 8; ht++) {
            int col = ht * 16 + l15;
            bf16x8 b = *reinterpret_cast<const bf16x8*>(W1t + (size_t)col * D_DIM + ks * 32 + lhi * 8);
            acc[ht] = __builtin_amdgcn_mfma_f32_16x16x32_bf16(a, b, acc[ht], 0, 0, 0);
        }
    }
    float part = 0.f;
    #pragma unroll
    for (int ht = 0; ht < 8; ht++) {
        int col = ht * 16 + l15;
        float bb = b1[col], w2 = W2[col];
        #pragma unroll
        for (int reg = 0; reg < 4; reg++) {
            int row = r0 + lhi * 4 + reg;
            if (row < N_NODES) part += tanhf(acc[ht][reg] + bb) * w2;
        }
    }
    #pragma unroll
    for (int off = 1; off < 64; off <<= 1) part += __shfl_xor(part, off);
    if (lane == 0) atomicAdd(&wsum[m], part);
}

__global__ void compute_beta(const float* __restrict__ wsum, float* __restrict__ beta) {
    float w0 = wsum[0] / N_NODES, w1 = wsum[1] / N_NODES, w2 = wsum[2] / N_NODES;
    float mx = fmaxf(w0, fmaxf(w1, w2));
    float e0 = expf(w0 - mx), e1 = expf(w1 - mx), e2 = expf(w2 - mx);
    float s = e0 + e1 + e2;
    beta[0] = e0 / s; beta[1] = e1 / s; beta[2] = e2 / s;
}

// ------- final: out = sum_m beta[m] * zb[m] (bf16 -> fp32), 2 comps/thread -------
__global__ void final_mix(const unsigned* __restrict__ zb, const float* __restrict__ beta,
                          float* __restrict__ out) {
    int i = blockIdx.x * blockDim.x + threadIdx.x;   // u32 index
    if (i >= N_NODES * (D_DIM / 2)) return;
    const size_t stride = (size_t)N_NODES * (D_DIM / 2);
    float b0 = beta[0], b1 = beta[1], b2 = beta[2];
    unsigned w0 = zb[i], w1 = zb[stride + i], w2 = zb[2 * stride + i];
    float2 r;
    r.x = b0 * bflo(w0) + b1 * bflo(w1) + b2 * bflo(w2);
    r.y = b0 * bfhi(w0) + b1 * bfhi(w1) + b2 * bfhi(w2);
    ((float2*)out)[i] = r;
}

extern "C" void kernel_launch(void* const* d_in, const int* in_sizes, int n_in,
                              void* d_out, int out_size, void* d_ws, size_t ws_size,
                              hipStream_t stream) {
    const float* h        = (const float*)d_in[0];
    const int*   eidx     = (const int*)d_in[1];
    const float* W        = (const float*)d_in[2];
    const float* attn_l   = (const float*)d_in[3];
    const float* attn_r   = (const float*)d_in[4];
    const float* bias     = (const float*)d_in[5];
    const float* sem_W1   = (const float*)d_in[6];
    const float* sem_b1   = (const float*)d_in[7];
    const float* sem_W2   = (const float*)d_in[8];
    float* out = (float*)d_out;

    float* ws = (float*)d_ws;
    float* el   = ws;                                      // N*H
    float* er   = el + N_NODES * H_HEADS;                  // N*H
    float* wsum = er + N_NODES * H_HEADS;                  // 8
    float* beta = wsum + 8;                                // 8
    unsigned short* featb = (unsigned short*)(beta + 8);           // N*D bf16      25.6 MB
    unsigned short* zb    = featb + (size_t)N_NODES * D_DIM;       // M*N*D bf16    76.8 MB
    unsigned short* Wt    = zb + (size_t)M_PATHS * N_NODES * D_DIM;  // M*D*IN bf16
    unsigned short* W1t   = Wt + (size_t)M_PATHS * D_DIM * IN_F;     // HID*D bf16
    int* bsrc3   = (int*)(W1t + (size_t)HID_DIM * D_DIM);  // M*E
    int* rowptr3 = bsrc3 + (size_t)M_PATHS * E_EDGES;      // M*(N+1)
    int* deg3    = rowptr3 + M_PATHS * (N_NODES + 1);      // M*N
    int* cursor3 = deg3 + M_PATHS * N_NODES;               // M*N

    hipMemsetAsync(wsum, 0, 16 * sizeof(float), stream);
    hipMemsetAsync(deg3, 0, 2 * M_PATHS * N_NODES * sizeof(int), stream);  // deg3+cursor3

    // one-time weight prep
    transpose_w<<<dim3((IN_F * D_DIM + 255) / 256, M_PATHS), 256, 0, stream>>>(
        W, Wt, IN_F, D_DIM);
    transpose_w<<<dim3((D_DIM * HID_DIM + 255) / 256, 1), 256, 0, stream>>>(
        sem_W1, W1t, D_DIM, HID_DIM);

    // batched CSR build (feature-independent)
    count_all<<<dim3((E_EDGES + 255) / 256, M_PATHS), 256, 0, stream>>>(eidx, deg3);
    exscan_all<<<M_PATHS, SCAN_T, 0, stream>>>(deg3, rowptr3);
    fill_all<<<dim3((E_EDGES + 255) / 256, M_PATHS), 256, 0, stream>>>(
        eidx, rowptr3, cursor3, bsrc3);

    for (int m = 0; m < M_PATHS; ++m) {
        const float* hm = h + (size_t)m * N_NODES * IN_F;
        unsigned short* zbm = zb + (size_t)m * N_NODES * D_DIM;

        gemm_feat_mfma<<<(N_NODES + 63) / 64, 256, 0, stream>>>(
            hm, Wt + (size_t)m * D_DIM * IN_F, featb);

        attn_dots<<<(N_NODES * H_HEADS + 255) / 256, 256, 0, stream>>>(
            (const unsigned*)featb, attn_l + m * H_HEADS * O_DIM,
            attn_r + m * H_HEADS * O_DIM, el, er);

        gather_z<<<N_NODES / 2, 128, 0, stream>>>(
            rowptr3 + m * (N_NODES + 1), bsrc3 + (size_t)m * E_EDGES, el, er,
            (const uint2*)featb, bias + m * D_DIM, (uint2*)zbm);

        semantic_mfma<<<(N_NODES + 63) / 64, 256, 0, stream>>>(
            zbm, W1t, sem_b1, sem_W2, wsum, m);
    }

    compute_beta<<<1, 1, 0, stream>>>(wsum, beta);
    final_mix<<<(N_NODES * (D_DIM / 2) + 255) / 256, 256, 0, stream>>>(
        (const unsigned*)zb, beta, out);
}

// Round 6
// 849.599 us; speedup vs baseline: 3.2519x; 1.1930x over previous
//
#include <hip/hip_runtime.h>
#include <hip/hip_bf16.h>
#include <math.h>
#include <string.h>

#define N_NODES 50000
#define E_EDGES 800000
#define M_PATHS 3
#define IN_F    128
#define H_HEADS 8
#define O_DIM   32
#define D_DIM   256   // H*O
#define HID_DIM 128
#define NEG_SLOPE 0.2f
#define SCAN_BLK 256
#define SCAN_NB  ((N_NODES + SCAN_BLK - 1) / SCAN_BLK)   // 196

typedef __attribute__((ext_vector_type(8))) short bf16x8;
typedef __attribute__((ext_vector_type(4))) float f32x4;

__device__ __forceinline__ float bflo(unsigned w) { return __uint_as_float(w << 16); }
__device__ __forceinline__ float bfhi(unsigned w) { return __uint_as_float(w & 0xffff0000u); }

__device__ __forceinline__ unsigned short f2bf(float f) {
    __hip_bfloat16 hb = __float2bfloat16(f);
    unsigned short us;
    memcpy(&us, &hb, 2);
    return us;
}
__device__ __forceinline__ unsigned pk_bf16(float a, float b) {
    return (unsigned)f2bf(a) | ((unsigned)f2bf(b) << 16);
}

__device__ __forceinline__ bf16x8 cvt_frag(const float* __restrict__ p) {
    union { unsigned short u[8]; bf16x8 v; } r;
    const float4 f0 = *reinterpret_cast<const float4*>(p);
    const float4 f1 = *reinterpret_cast<const float4*>(p + 4);
    r.u[0] = f2bf(f0.x); r.u[1] = f2bf(f0.y); r.u[2] = f2bf(f0.z); r.u[3] = f2bf(f0.w);
    r.u[4] = f2bf(f1.x); r.u[5] = f2bf(f1.y); r.u[6] = f2bf(f1.z); r.u[7] = f2bf(f1.w);
    return r.v;
}
__device__ __forceinline__ bf16x8 zero_frag() {
    union { unsigned short u[8]; bf16x8 v; } r = {};
    return r.v;
}

// residue (blockIdx%8) -> (metapath, range-class, nclasses)
__device__ __forceinline__ void residue_map(int res, int& m, int& c, int& r) {
    m = res < 3 ? 0 : (res < 6 ? 1 : 2);
    c = res - (m == 0 ? 0 : (m == 1 ? 3 : 6));
    r = (m == 2) ? 2 : 3;
}

// ------- batched transpose-convert: W[m] [K][C] fp32 -> Wt[m] [C][K] bf16 -------
__global__ void transpose_w(const float* __restrict__ in, unsigned short* __restrict__ out,
                            int K, int C) {
    const int m = blockIdx.y;
    int i = blockIdx.x * blockDim.x + threadIdx.x;
    if (i >= K * C) return;
    int k = i / C, c = i % C;
    out[(size_t)m * K * C + (size_t)c * K + k] = f2bf(in[(size_t)m * K * C + i]);
}

// ------- GEMM: featb(bf16) = h @ W via MFMA -------
__global__ __launch_bounds__(256) void gemm_feat_mfma(const float* __restrict__ h,
                                                      const unsigned short* __restrict__ Wt,
                                                      unsigned short* __restrict__ featb) {
    const int wave = threadIdx.x >> 6;
    const int lane = threadIdx.x & 63;
    const int l15 = lane & 15, lhi = lane >> 4;
    const int r0 = blockIdx.x * 64;
    const int c0 = wave * 64;
    f32x4 acc[4][4] = {};

    for (int ks = 0; ks < 4; ++ks) {
        bf16x8 a[4], b[4];
        #pragma unroll
        for (int rg = 0; rg < 4; rg++) {
            int row = r0 + rg * 16 + l15;
            a[rg] = (row < N_NODES) ? cvt_frag(h + (size_t)row * IN_F + ks * 32 + lhi * 8)
                                    : zero_frag();
        }
        #pragma unroll
        for (int ct = 0; ct < 4; ct++) {
            int col = c0 + ct * 16 + l15;
            b[ct] = *reinterpret_cast<const bf16x8*>(Wt + (size_t)col * IN_F + ks * 32 + lhi * 8);
        }
        #pragma unroll
        for (int rg = 0; rg < 4; rg++)
            #pragma unroll
            for (int ct = 0; ct < 4; ct++)
                acc[rg][ct] = __builtin_amdgcn_mfma_f32_16x16x32_bf16(a[rg], b[ct], acc[rg][ct], 0, 0, 0);
    }
    #pragma unroll
    for (int rg = 0; rg < 4; rg++) {
        #pragma unroll
        for (int reg = 0; reg < 4; reg++) {
            int row = r0 + rg * 16 + lhi * 4 + reg;
            if (row < N_NODES) {
                #pragma unroll
                for (int ct = 0; ct < 4; ct++) {
                    int col = c0 + ct * 16 + l15;
                    featb[(size_t)row * D_DIM + col] = f2bf(acc[rg][ct][reg]);
                }
            }
        }
    }
}

// ------- el/er -------
__global__ void attn_dots(const unsigned* __restrict__ featb,
                          const float* __restrict__ al,
                          const float* __restrict__ ar,
                          float* __restrict__ el, float* __restrict__ er) {
    int idx = blockIdx.x * blockDim.x + threadIdx.x;
    if (idx >= N_NODES * H_HEADS) return;
    int n = idx / H_HEADS, hh = idx % H_HEADS;
    const uint4* fv = (const uint4*)(featb + (size_t)n * (D_DIM / 2) + hh * (O_DIM / 2));
    const float* a = al + hh * O_DIM;
    const float* b = ar + hh * O_DIM;
    float sl = 0.f, sr = 0.f;
    #pragma unroll
    for (int q = 0; q < 4; q++) {
        uint4 v = fv[q];
        unsigned ws4[4] = {v.x, v.y, v.z, v.w};
        #pragma unroll
        for (int k = 0; k < 4; k++) {
            int o = q * 8 + k * 2;
            float f0 = bflo(ws4[k]), f1 = bfhi(ws4[k]);
            sl += f0 * a[o] + f1 * a[o + 1];
            sr += f0 * b[o] + f1 * b[o + 1];
        }
    }
    el[idx] = sl; er[idx] = sr;
}

// ------- CSR: count (dst-range partitioned, XCD-local atomics) -------
__global__ __launch_bounds__(256) void count_all(const int* __restrict__ eidx,
                                                 int* __restrict__ deg3) {
    int m, c, r;
    residue_map(blockIdx.x & 7, m, c, r);
    const int lo = c * N_NODES / r, hi = (c + 1) * N_NODES / r;
    const int bpc = gridDim.x >> 3;
    const int w = blockIdx.x >> 3;
    const int* dst = eidx + (size_t)m * 2 * E_EDGES + E_EDGES;
    int* deg = deg3 + m * N_NODES;
    for (int e = w * 256 + threadIdx.x; e < E_EDGES; e += bpc * 256) {
        int d = dst[e];
        if (d >= lo && d < hi) atomicAdd(&deg[d], 1);
    }
}

// ------- scan phase A: per-block partial sums -------
__global__ __launch_bounds__(256) void scan_partial(const int* __restrict__ deg3,
                                                    int* __restrict__ psum) {
    const int m = blockIdx.y, b = blockIdx.x, t = threadIdx.x;
    int i = b * SCAN_BLK + t;
    int v = (i < N_NODES) ? deg3[m * N_NODES + i] : 0;
    #pragma unroll
    for (int off = 1; off < 64; off <<= 1) v += __shfl_xor(v, off);
    __shared__ int red[4];
    if ((t & 63) == 0) red[t >> 6] = v;
    __syncthreads();
    if (t == 0) psum[m * gridDim.x + b] = red[0] + red[1] + red[2] + red[3];
}

// ------- scan phase B: exscan the partials (one block per metapath) -------
__global__ __launch_bounds__(256) void scan_offsets(int* __restrict__ psum,
                                                    int* __restrict__ rowptr3) {
    const int m = blockIdx.x, t = threadIdx.x;
    __shared__ int sh[256];
    int v = (t < SCAN_NB) ? psum[m * SCAN_NB + t] : 0;
    sh[t] = v;
    __syncthreads();
    for (int off = 1; off < 256; off <<= 1) {
        int u = (t >= off) ? sh[t - off] : 0;
        __syncthreads();
        sh[t] += u;
        __syncthreads();
    }
    if (t < SCAN_NB) psum[m * SCAN_NB + t] = sh[t] - v;   // exclusive
    if (t == 255) rowptr3[m * (N_NODES + 1) + N_NODES] = sh[255];
}

// ------- scan phase C: rowptr = block offset + local exscan -------
__global__ __launch_bounds__(256) void scan_final(const int* __restrict__ deg3,
                                                  const int* __restrict__ psum,
                                                  int* __restrict__ rowptr3) {
    const int m = blockIdx.y, b = blockIdx.x, t = threadIdx.x;
    int i = b * SCAN_BLK + t;
    int v = (i < N_NODES) ? deg3[m * N_NODES + i] : 0;
    __shared__ int sh[256];
    sh[t] = v;
    __syncthreads();
    for (int off = 1; off < 256; off <<= 1) {
        int u = (t >= off) ? sh[t - off] : 0;
        __syncthreads();
        sh[t] += u;
        __syncthreads();
    }
    if (i < N_NODES) rowptr3[m * (N_NODES + 1) + i] = psum[m * SCAN_NB + b] + sh[t] - v;
}

// ------- CSR: fill (dst-range partitioned; cursor pre-init = rowptr) -------
__global__ __launch_bounds__(256) void fill_all(const int* __restrict__ eidx,
                                                int* __restrict__ cursor3,
                                                int* __restrict__ bsrc3) {
    int m, c, r;
    residue_map(blockIdx.x & 7, m, c, r);
    const int lo = c * N_NODES / r, hi = (c + 1) * N_NODES / r;
    const int bpc = gridDim.x >> 3;
    const int w = blockIdx.x >> 3;
    const int* src = eidx + (size_t)m * 2 * E_EDGES;
    const int* dst = src + E_EDGES;
    int* cur = cursor3 + m * (N_NODES + 1);
    int* bs = bsrc3 + (size_t)m * E_EDGES;
    for (int e = w * 256 + threadIdx.x; e < E_EDGES; e += bpc * 256) {
        int d = dst[e];
        if (d >= lo && d < hi) {
            int j = atomicAdd(&cur[d], 1);
            bs[j] = src[e];
        }
    }
}

// ------- gather: 1 wave/node, 4 nodes/block, 2-edge unroll, bf16 z out -------
__global__ __launch_bounds__(256) void gather_z(const int* __restrict__ rowptr,
                                                const int* __restrict__ bsrc,
                                                const float* __restrict__ el,
                                                const float* __restrict__ er,
                                                const uint2* __restrict__ featb2,
                                                const float* __restrict__ bias,
                                                uint2* __restrict__ zb2) {
    const int wid = threadIdx.x >> 6;
    const int l = threadIdx.x & 63;
    const int d = blockIdx.x * 4 + wid;
    const int vh = l & 7;               // virtual head this lane evaluates exp for
    const int hh = l >> 3;              // head this lane's components belong to
    const int j0 = rowptr[d], j1 = rowptr[d + 1];
    const float erv = er[d * H_HEADS + vh];

    float den = 0.f, a0 = 0.f, a1 = 0.f, a2 = 0.f, a3 = 0.f;
    int j = j0;
    for (; j + 2 <= j1; j += 2) {
        int s0 = bsrc[j], s1 = bsrc[j + 1];
        float y0 = el[s0 * H_HEADS + vh] + erv;
        float y1 = el[s1 * H_HEADS + vh] + erv;
        uint2 w0 = featb2[(size_t)s0 * 64 + l];
        uint2 w1 = featb2[(size_t)s1 * 64 + l];
        y0 = fmaxf(y0, NEG_SLOPE * y0);
        y1 = fmaxf(y1, NEG_SLOPE * y1);
        float q0 = __expf(y0), q1 = __expf(y1);
        float ex0 = __shfl(q0, hh), ex1 = __shfl(q1, hh);
        den += ex0 + ex1;
        a0 += ex0 * bflo(w0.x) + ex1 * bflo(w1.x);
        a1 += ex0 * bfhi(w0.x) + ex1 * bfhi(w1.x);
        a2 += ex0 * bflo(w0.y) + ex1 * bflo(w1.y);
        a3 += ex0 * bfhi(w0.y) + ex1 * bfhi(w1.y);
    }
    if (j < j1) {
        int s = bsrc[j];
        float y = el[s * H_HEADS + vh] + erv;
        uint2 w = featb2[(size_t)s * 64 + l];
        y = fmaxf(y, NEG_SLOPE * y);
        float ex = __shfl(__expf(y), hh);
        den += ex;
        a0 += ex * bflo(w.x); a1 += ex * bfhi(w.x);
        a2 += ex * bflo(w.y); a3 += ex * bfhi(w.y);
    }
    float inv = 1.f / (den == 0.f ? 1.f : den);
    float4 b4 = ((const float4*)bias)[l];
    float x0 = a0 * inv + b4.x;
    float x1 = a1 * inv + b4.y;
    float x2 = a2 * inv + b4.z;
    float x3 = a3 * inv + b4.w;
    x0 = x0 > 0.f ? x0 : expm1f(x0);
    x1 = x1 > 0.f ? x1 : expm1f(x1);
    x2 = x2 > 0.f ? x2 : expm1f(x2);
    x3 = x3 > 0.f ? x3 : expm1f(x3);
    uint2 r;
    r.x = pk_bf16(x0, x1);
    r.y = pk_bf16(x2, x3);
    zb2[(size_t)d * 64 + l] = r;
}

// ------- semantic attention via MFMA on bf16 z -------
__global__ __launch_bounds__(256) void semantic_mfma(const unsigned short* __restrict__ zb,
                                                     const unsigned short* __restrict__ W1t,
                                                     const float* __restrict__ b1,
                                                     const float* __restrict__ W2,
                                                     float* __restrict__ wsum, int m) {
    const int wave = threadIdx.x >> 6;
    const int lane = threadIdx.x & 63;
    const int l15 = lane & 15, lhi = lane >> 4;
    const int r0 = blockIdx.x * 64 + wave * 16;
    f32x4 acc[8] = {};

    for (int ks = 0; ks < 8; ++ks) {
        int row = r0 + l15;
        bf16x8 a = (row < N_NODES)
            ? *reinterpret_cast<const bf16x8*>(zb + (size_t)row * D_DIM + ks * 32 + lhi * 8)
            : zero_frag();
        #pragma unroll
        for (int ht = 0; ht < 8; ht++) {
            int col = ht * 16 + l15;
            bf16x8 b = *reinterpret_cast<const bf16x8*>(W1t + (size_t)col * D_DIM + ks * 32 + lhi * 8);
            acc[ht] = __builtin_amdgcn_mfma_f32_16x16x32_bf16(a, b, acc[ht], 0, 0, 0);
        }
    }
    float part = 0.f;
    #pragma unroll
    for (int ht = 0; ht < 8; ht++) {
        int col = ht * 16 + l15;
        float bb = b1[col], w2 = W2[col];
        #pragma unroll
        for (int reg = 0; reg < 4; reg++) {
            int row = r0 + lhi * 4 + reg;
            if (row < N_NODES) part += tanhf(acc[ht][reg] + bb) * w2;
        }
    }
    #pragma unroll
    for (int off = 1; off < 64; off <<= 1) part += __shfl_xor(part, off);
    if (lane == 0) atomicAdd(&wsum[m], part);
}

__global__ void compute_beta(const float* __restrict__ wsum, float* __restrict__ beta) {
    float w0 = wsum[0] / N_NODES, w1 = wsum[1] / N_NODES, w2 = wsum[2] / N_NODES;
    float mx = fmaxf(w0, fmaxf(w1, w2));
    float e0 = expf(w0 - mx), e1 = expf(w1 - mx), e2 = expf(w2 - mx);
    float s = e0 + e1 + e2;
    beta[0] = e0 / s; beta[1] = e1 / s; beta[2] = e2 / s;
}

__global__ void final_mix(const unsigned* __restrict__ zb, const float* __restrict__ beta,
                          float* __restrict__ out) {
    int i = blockIdx.x * blockDim.x + threadIdx.x;
    if (i >= N_NODES * (D_DIM / 2)) return;
    const size_t stride = (size_t)N_NODES * (D_DIM / 2);
    float b0 = beta[0], b1 = beta[1], b2 = beta[2];
    unsigned w0 = zb[i], w1 = zb[stride + i], w2 = zb[2 * stride + i];
    float2 r;
    r.x = b0 * bflo(w0) + b1 * bflo(w1) + b2 * bflo(w2);
    r.y = b0 * bfhi(w0) + b1 * bfhi(w1) + b2 * bfhi(w2);
    ((float2*)out)[i] = r;
}

extern "C" void kernel_launch(void* const* d_in, const int* in_sizes, int n_in,
                              void* d_out, int out_size, void* d_ws, size_t ws_size,
                              hipStream_t stream) {
    const float* h        = (const float*)d_in[0];
    const int*   eidx     = (const int*)d_in[1];
    const float* W        = (const float*)d_in[2];
    const float* attn_l   = (const float*)d_in[3];
    const float* attn_r   = (const float*)d_in[4];
    const float* bias     = (const float*)d_in[5];
    const float* sem_W1   = (const float*)d_in[6];
    const float* sem_b1   = (const float*)d_in[7];
    const float* sem_W2   = (const float*)d_in[8];
    float* out = (float*)d_out;

    float* ws = (float*)d_ws;
    float* el   = ws;                                      // N*H
    float* er   = el + N_NODES * H_HEADS;                  // N*H
    float* wsum = er + N_NODES * H_HEADS;                  // 8
    float* beta = wsum + 8;                                // 8
    unsigned short* featb = (unsigned short*)(beta + 8);           // N*D bf16
    unsigned short* zb    = featb + (size_t)N_NODES * D_DIM;       // M*N*D bf16
    unsigned short* Wt    = zb + (size_t)M_PATHS * N_NODES * D_DIM;
    unsigned short* W1t   = Wt + (size_t)M_PATHS * D_DIM * IN_F;
    int* bsrc3   = (int*)(W1t + (size_t)HID_DIM * D_DIM);  // M*E
    int* rowptr3 = bsrc3 + (size_t)M_PATHS * E_EDGES;      // M*(N+1)
    int* cursor3 = rowptr3 + M_PATHS * (N_NODES + 1);      // M*(N+1)
    int* deg3    = cursor3 + M_PATHS * (N_NODES + 1);      // M*N
    int* psum    = deg3 + M_PATHS * N_NODES;               // M*SCAN_NB

    hipMemsetAsync(wsum, 0, 16 * sizeof(float), stream);
    hipMemsetAsync(deg3, 0, M_PATHS * N_NODES * sizeof(int), stream);

    // one-time weight prep
    transpose_w<<<dim3((IN_F * D_DIM + 255) / 256, M_PATHS), 256, 0, stream>>>(
        W, Wt, IN_F, D_DIM);
    transpose_w<<<dim3((D_DIM * HID_DIM + 255) / 256, 1), 256, 0, stream>>>(
        sem_W1, W1t, D_DIM, HID_DIM);

    // batched CSR build, dst-range partitioned per XCD residue class
    count_all<<<2048, 256, 0, stream>>>(eidx, deg3);
    scan_partial<<<dim3(SCAN_NB, M_PATHS), 256, 0, stream>>>(deg3, psum);
    scan_offsets<<<M_PATHS, 256, 0, stream>>>(psum, rowptr3);
    scan_final<<<dim3(SCAN_NB, M_PATHS), 256, 0, stream>>>(deg3, psum, rowptr3);
    hipMemcpyAsync(cursor3, rowptr3, M_PATHS * (N_NODES + 1) * sizeof(int),
                   hipMemcpyDeviceToDevice, stream);
    fill_all<<<2048, 256, 0, stream>>>(eidx, cursor3, bsrc3);

    for (int m = 0; m < M_PATHS; ++m) {
        const float* hm = h + (size_t)m * N_NODES * IN_F;
        unsigned short* zbm = zb + (size_t)m * N_NODES * D_DIM;

        gemm_feat_mfma<<<(N_NODES + 63) / 64, 256, 0, stream>>>(
            hm, Wt + (size_t)m * D_DIM * IN_F, featb);

        attn_dots<<<(N_NODES * H_HEADS + 255) / 256, 256, 0, stream>>>(
            (const unsigned*)featb, attn_l + m * H_HEADS * O_DIM,
            attn_r + m * H_HEADS * O_DIM, el, er);

        gather_z<<<N_NODES / 4, 256, 0, stream>>>(
            rowptr3 + m * (N_NODES + 1), bsrc3 + (size_t)m * E_EDGES, el, er,
            (const uint2*)featb, bias + m * D_DIM, (uint2*)zbm);

        semantic_mfma<<<(N_NODES + 63) / 64, 256, 0, stream>>>(
            zbm, W1t, sem_b1, sem_W2, wsum, m);
    }

    compute_beta<<<1, 1, 0, stream>>>(wsum, beta);
    final_mix<<<(N_NODES * (D_DIM / 2) + 255) / 256, 256, 0, stream>>>(
        (const unsigned*)zb, beta, out);
}